// Round 1
// baseline (1790.172 us; speedup 1.0000x reference)
//
#include <hip/hip_runtime.h>
#include <cstdint>
#include <cstddef>

#define ALPHA 0.2f
#define MLP_SLOPE 0.01f

__device__ __forceinline__ float lrelu(float x, float s) { return x > 0.f ? x : x * s; }
__device__ __forceinline__ void fma4(float4& a, float s, const float4& b) {
  a.x = fmaf(s, b.x, a.x); a.y = fmaf(s, b.y, a.y);
  a.z = fmaf(s, b.z, a.z); a.w = fmaf(s, b.w, a.w);
}
__device__ __forceinline__ void add4(float4& a, const float4& b) {
  a.x += b.x; a.y += b.y; a.z += b.z; a.w += b.w;
}
__device__ __forceinline__ void lr4(float4& a, float s) {
  a.x = lrelu(a.x, s); a.y = lrelu(a.y, s); a.z = lrelu(a.z, s); a.w = lrelu(a.w, s);
}

// ---------------------------------------------------------------------------
// Generic fp32 GEMM: C = act(A[M,K] @ B[K,N] + bias), 128x128 tile, 8x8 micro
// ---------------------------------------------------------------------------
__global__ __launch_bounds__(256) void gemm128(
    const float* __restrict__ A, const float* __restrict__ B,
    const float* __restrict__ bias, float* __restrict__ C,
    int M, int N, int K, size_t asz, size_t bsz, size_t csz,
    float slope, int act)
{
  __shared__ float As[16 * 128];   // [k][m]
  __shared__ float Bs[16 * 128];   // [k][n]
  const float* Ab = A + (size_t)blockIdx.z * asz;
  const float* Bb = B + (size_t)blockIdx.z * bsz;
  float* Cb = C + (size_t)blockIdx.z * csz;
  const int t = threadIdx.x;
  const int bm = blockIdx.y * 128, bn = blockIdx.x * 128;
  const int tx = t & 15, ty = t >> 4;
  float4 acc[8][2];
#pragma unroll
  for (int i = 0; i < 8; ++i) {
    acc[i][0] = make_float4(0.f, 0.f, 0.f, 0.f);
    acc[i][1] = make_float4(0.f, 0.f, 0.f, 0.f);
  }
  for (int k0 = 0; k0 < K; k0 += 16) {
    __syncthreads();
#pragma unroll
    for (int m = 0; m < 2; ++m) {
      int f = m * 256 + t;
      int r = f >> 2, c4 = (f & 3) << 2;
      float4 av = *(const float4*)&Ab[(size_t)(bm + r) * K + k0 + c4];
      As[(c4 + 0) * 128 + r] = av.x;
      As[(c4 + 1) * 128 + r] = av.y;
      As[(c4 + 2) * 128 + r] = av.z;
      As[(c4 + 3) * 128 + r] = av.w;
      int br = f >> 5, bc = (f & 31) << 2;
      *(float4*)&Bs[br * 128 + bc] = *(const float4*)&Bb[(size_t)(k0 + br) * N + bn + bc];
    }
    __syncthreads();
#pragma unroll
    for (int k = 0; k < 16; ++k) {
      float4 a0 = *(const float4*)&As[k * 128 + ty * 8];
      float4 a1 = *(const float4*)&As[k * 128 + ty * 8 + 4];
      float4 b0 = *(const float4*)&Bs[k * 128 + tx * 8];
      float4 b1 = *(const float4*)&Bs[k * 128 + tx * 8 + 4];
      fma4(acc[0][0], a0.x, b0); fma4(acc[0][1], a0.x, b1);
      fma4(acc[1][0], a0.y, b0); fma4(acc[1][1], a0.y, b1);
      fma4(acc[2][0], a0.z, b0); fma4(acc[2][1], a0.z, b1);
      fma4(acc[3][0], a0.w, b0); fma4(acc[3][1], a0.w, b1);
      fma4(acc[4][0], a1.x, b0); fma4(acc[4][1], a1.x, b1);
      fma4(acc[5][0], a1.y, b0); fma4(acc[5][1], a1.y, b1);
      fma4(acc[6][0], a1.z, b0); fma4(acc[6][1], a1.z, b1);
      fma4(acc[7][0], a1.w, b0); fma4(acc[7][1], a1.w, b1);
    }
  }
  float4 bv0 = make_float4(0.f, 0.f, 0.f, 0.f);
  float4 bv1 = bv0;
  if (bias) {
    bv0 = *(const float4*)&bias[bn + tx * 8];
    bv1 = *(const float4*)&bias[bn + tx * 8 + 4];
  }
#pragma unroll
  for (int i = 0; i < 8; ++i) {
    int row = bm + ty * 8 + i;
    float4 v0 = acc[i][0], v1 = acc[i][1];
    add4(v0, bv0); add4(v1, bv1);
    if (act) { lr4(v0, slope); lr4(v1, slope); }
    *(float4*)&Cb[(size_t)row * N + bn + tx * 8] = v0;
    *(float4*)&Cb[(size_t)row * N + bn + tx * 8 + 4] = v1;
  }
}

// ---------------------------------------------------------------------------
// s1/s2: per-row dots of h with a1/a2 (one wave per row, both heads)
// ---------------------------------------------------------------------------
__global__ __launch_bounds__(256) void s_kernel(
    const float* __restrict__ hbuf, const float* __restrict__ a1,
    const float* __restrict__ a2, float* __restrict__ s1, float* __restrict__ s2)
{
  const int gw = (blockIdx.x * 256 + threadIdx.x) >> 6;   // row 0..8191
  const int lane = threadIdx.x & 63;
#pragma unroll
  for (int hh = 0; hh < 2; ++hh) {
    float4 hv = ((const float4*)(hbuf + ((size_t)hh * 8192 + gw) * 256))[lane];
    float4 a1v = ((const float4*)(a1 + hh * 256))[lane];
    float4 a2v = ((const float4*)(a2 + hh * 256))[lane];
    float p1 = hv.x * a1v.x + hv.y * a1v.y + hv.z * a1v.z + hv.w * a1v.w;
    float p2 = hv.x * a2v.x + hv.y * a2v.y + hv.z * a2v.z + hv.w * a2v.w;
    for (int off = 32; off > 0; off >>= 1) {
      p1 += __shfl_xor(p1, off);
      p2 += __shfl_xor(p2, off);
    }
    if (lane == 0) {
      s1[hh * 8192 + gw] = p1;
      s2[hh * 8192 + gw] = p2;
    }
  }
}

// ---------------------------------------------------------------------------
// Attention: per block 32 out-rows x 256 cols x 2 heads over half the j-range.
// w_ij = adj>0 ? exp(leaky_relu(s1_i+s2_j)) : 0 (no max-sub: |score| <= ~8).
// Writes partial numerators (pacc) and denominators (pl).
// ---------------------------------------------------------------------------
__global__ __launch_bounds__(256) void attn_kernel(
    const float* __restrict__ hbuf, const float* __restrict__ s1g,
    const float* __restrict__ s2g, const int* __restrict__ adj,
    float* __restrict__ pacc, float* __restrict__ pl)
{
  constexpr int TJ = 16;
  __shared__ float sh_h[2 * TJ * 256];   // [head][jj][c]
  __shared__ float sh_w[2 * TJ * 32];    // [head][jj][r]  (transposed: broadcast reads)
  __shared__ float sh_l[64];
  const int t = threadIdx.x;
  const int row0 = blockIdx.x * 32;
  const int jhalf = blockIdx.y;
  const int jbeg = jhalf * 4096;
  const int sr = t >> 3;          // staging row 0..31
  const int sj = (t & 7) * 2;     // staging jj pair
  const float s1_0 = s1g[row0 + sr];
  const float s1_1 = s1g[8192 + row0 + sr];
  const int cg = t & 63;          // col group (4 cols)
  const int rg = t >> 6;          // row group (8 rows)
  float4 acc0[8], acc1[8];
#pragma unroll
  for (int i = 0; i < 8; ++i) {
    acc0[i] = make_float4(0.f, 0.f, 0.f, 0.f);
    acc1[i] = make_float4(0.f, 0.f, 0.f, 0.f);
  }
  float lp0 = 0.f, lp1 = 0.f;
  for (int jt = 0; jt < 4096 / TJ; ++jt) {
    const int j0 = jbeg + jt * TJ;
    __syncthreads();
    // stage h tiles (both heads): 2*16*256 floats = 8 float4 per thread
#pragma unroll
    for (int m = 0; m < 8; ++m) {
      int f = m * 256 + t;
      int hh = f >> 10;
      int rem = f & 1023;
      int jj = rem >> 6;
      int c4 = rem & 63;
      ((float4*)sh_h)[f] =
          *(const float4*)&hbuf[((size_t)hh * 8192 + j0 + jj) * 256 + c4 * 4];
    }
    // stage w: adj read ONCE, shared by both heads
    const int2 av = *(const int2*)&adj[(size_t)(row0 + sr) * 8192 + j0 + sj];
    const float s20a = s2g[j0 + sj], s20b = s2g[j0 + sj + 1];
    const float s21a = s2g[8192 + j0 + sj], s21b = s2g[8192 + j0 + sj + 1];
    float w00 = av.x > 0 ? __expf(lrelu(s1_0 + s20a, ALPHA)) : 0.f;
    float w01 = av.y > 0 ? __expf(lrelu(s1_0 + s20b, ALPHA)) : 0.f;
    float w10 = av.x > 0 ? __expf(lrelu(s1_1 + s21a, ALPHA)) : 0.f;
    float w11 = av.y > 0 ? __expf(lrelu(s1_1 + s21b, ALPHA)) : 0.f;
    sh_w[(0 * TJ + sj) * 32 + sr] = w00;
    sh_w[(0 * TJ + sj + 1) * 32 + sr] = w01;
    sh_w[(1 * TJ + sj) * 32 + sr] = w10;
    sh_w[(1 * TJ + sj + 1) * 32 + sr] = w11;
    lp0 += w00 + w01;
    lp1 += w10 + w11;
    __syncthreads();
#pragma unroll
    for (int jj = 0; jj < TJ; ++jj) {
      float4 h0 = ((const float4*)sh_h)[jj * 64 + cg];
      float4 h1 = ((const float4*)sh_h)[TJ * 64 + jj * 64 + cg];
      float4 wa0 = *(const float4*)&sh_w[(0 * TJ + jj) * 32 + rg * 8];
      float4 wb0 = *(const float4*)&sh_w[(0 * TJ + jj) * 32 + rg * 8 + 4];
      float4 wa1 = *(const float4*)&sh_w[(1 * TJ + jj) * 32 + rg * 8];
      float4 wb1 = *(const float4*)&sh_w[(1 * TJ + jj) * 32 + rg * 8 + 4];
      fma4(acc0[0], wa0.x, h0); fma4(acc0[1], wa0.y, h0);
      fma4(acc0[2], wa0.z, h0); fma4(acc0[3], wa0.w, h0);
      fma4(acc0[4], wb0.x, h0); fma4(acc0[5], wb0.y, h0);
      fma4(acc0[6], wb0.z, h0); fma4(acc0[7], wb0.w, h0);
      fma4(acc1[0], wa1.x, h1); fma4(acc1[1], wa1.y, h1);
      fma4(acc1[2], wa1.z, h1); fma4(acc1[3], wa1.w, h1);
      fma4(acc1[4], wb1.x, h1); fma4(acc1[5], wb1.y, h1);
      fma4(acc1[6], wb1.z, h1); fma4(acc1[7], wb1.w, h1);
    }
  }
  __syncthreads();
  if (t < 64) sh_l[t] = 0.f;
  __syncthreads();
  atomicAdd(&sh_l[sr], lp0);
  atomicAdd(&sh_l[32 + sr], lp1);
  __syncthreads();
#pragma unroll
  for (int r8 = 0; r8 < 8; ++r8) {
    int row = row0 + rg * 8 + r8;
    *(float4*)&pacc[(((size_t)jhalf * 2 + 0) * 8192 + row) * 256 + cg * 4] = acc0[r8];
    *(float4*)&pacc[(((size_t)jhalf * 2 + 1) * 8192 + row) * 256 + cg * 4] = acc1[r8];
  }
  if (t < 32) {
    pl[((size_t)jhalf * 2 + 0) * 8192 + row0 + t] = sh_l[t];
    pl[((size_t)jhalf * 2 + 1) * 8192 + row0 + t] = sh_l[32 + t];
  }
}

// ---------------------------------------------------------------------------
// Finalize: combine j-halves, /l, leaky_relu, l2-normalize, +bias, head-mean
// -> embed[:, 512:768]
// ---------------------------------------------------------------------------
__global__ __launch_bounds__(256) void attn_finalize(
    const float* __restrict__ pacc, const float* __restrict__ pl,
    const float* __restrict__ bg, float* __restrict__ embed)
{
  __shared__ float red[256];
  const int r = blockIdx.x;
  const int t = threadIdx.x;
  float o[2], nrm[2];
#pragma unroll
  for (int hh = 0; hh < 2; ++hh) {
    float v = pacc[((size_t)hh * 8192 + r) * 256 + t] +
              pacc[((size_t)(2 + hh) * 8192 + r) * 256 + t];
    float l = pl[(size_t)hh * 8192 + r] + pl[(size_t)(2 + hh) * 8192 + r];
    o[hh] = lrelu(v / l, ALPHA);
  }
  for (int hh = 0; hh < 2; ++hh) {
    __syncthreads();
    red[t] = o[hh] * o[hh];
    __syncthreads();
    for (int s = 128; s > 0; s >>= 1) {
      if (t < s) red[t] += red[t + s];
      __syncthreads();
    }
    nrm[hh] = fmaxf(sqrtf(red[0]), 1e-12f);
  }
  embed[(size_t)r * 768 + 512 + t] =
      0.5f * (o[0] / nrm[0] + bg[t] + o[1] / nrm[1] + bg[256 + t]);
}

// ---------------------------------------------------------------------------
// Copy llm_emb into embed[:, 0:512]
// ---------------------------------------------------------------------------
__global__ __launch_bounds__(256) void copy_llm(
    const float* __restrict__ llm, float* __restrict__ embed)
{
  int idx = blockIdx.x * 256 + threadIdx.x;   // float4 id over 8192x512
  int r = idx >> 7, c = idx & 127;
  ((float4*)embed)[(size_t)r * 192 + c] = ((const float4*)llm)[idx];
}

// ---------------------------------------------------------------------------
// pred[e] = dot(z2[ts[e,0]], z2[ts[e,1]]) — one wave per edge
// ---------------------------------------------------------------------------
__global__ __launch_bounds__(256) void pred_kernel(
    const float* __restrict__ z2, const int* __restrict__ ts,
    float* __restrict__ out, int E)
{
  const int gw = (blockIdx.x * 256 + threadIdx.x) >> 6;
  const int lane = threadIdx.x & 63;
  if (gw >= E) return;
  const int a = ts[gw * 2], b = ts[gw * 2 + 1];
  float4 va = ((const float4*)(z2 + (size_t)a * 256))[lane];
  float4 vb = ((const float4*)(z2 + (size_t)b * 256))[lane];
  float p = va.x * vb.x + va.y * vb.y + va.z * vb.z + va.w * vb.w;
  for (int off = 32; off > 0; off >>= 1) p += __shfl_xor(p, off);
  if (lane == 0) out[gw] = p;
}

// ---------------------------------------------------------------------------
extern "C" void kernel_launch(void* const* d_in, const int* in_sizes, int n_in,
                              void* d_out, int out_size, void* d_ws, size_t ws_size,
                              hipStream_t stream) {
  const float* x   = (const float*)d_in[0];
  const int*   adj = (const int*)d_in[1];
  const int*   ts  = (const int*)d_in[2];
  const float* llm = (const float*)d_in[3];
  const float* Wg  = (const float*)d_in[4];
  const float* a1  = (const float*)d_in[5];
  const float* a2  = (const float*)d_in[6];
  const float* bg  = (const float*)d_in[7];
  const float* W1  = (const float*)d_in[8];
  const float* b1  = (const float*)d_in[9];
  const float* W2  = (const float*)d_in[10];
  const float* b2  = (const float*)d_in[11];
  float* out = (float*)d_out;
  float* ws  = (float*)d_ws;
  const int E = in_sizes[2] / 2;

  // workspace layout (floats)
  float* hbuf  = ws;                      // 2*8192*256   = 4,194,304
  float* s1    = hbuf + 4194304;          // 2*8192       = 16,384
  float* s2    = s1 + 16384;              // 16,384
  float* pacc  = s2 + 16384;              // 2*2*8192*256 = 8,388,608
  float* pl    = pacc + 8388608;          // 2*2*8192     = 32,768
  float* embed = pl + 32768;              // 8192*768     = 6,291,456
  float* z1    = embed + 6291456;         // 8192*512     = 4,194,304
  float* z2    = z1 + 4194304;            // 8192*256     = 2,097,152

  // 1. h[head] = x @ Wg[head]
  gemm128<<<dim3(2, 64, 2), 256, 0, stream>>>(
      x, Wg, nullptr, hbuf, 8192, 256, 512,
      (size_t)0, (size_t)512 * 256, (size_t)8192 * 256, 0.f, 0);
  // 2. s1/s2 row dots
  s_kernel<<<2048, 256, 0, stream>>>(hbuf, a1, a2, s1, s2);
  // 3. attention partials
  attn_kernel<<<dim3(256, 2), 256, 0, stream>>>(hbuf, s1, s2, adj, pacc, pl);
  // 4. embed[:, :512] = llm_emb
  copy_llm<<<4096, 256, 0, stream>>>(llm, embed);
  // 5. embed[:, 512:] = attention epilogue
  attn_finalize<<<8192, 256, 0, stream>>>(pacc, pl, bg, embed);
  // 6. z1 = LR(embed @ W1 + b1)
  gemm128<<<dim3(4, 64, 1), 256, 0, stream>>>(
      embed, W1, b1, z1, 8192, 512, 768, (size_t)0, (size_t)0, (size_t)0,
      MLP_SLOPE, 1);
  // 7. z2 = LR(z1 @ W2 + b2)
  gemm128<<<dim3(2, 64, 1), 256, 0, stream>>>(
      z1, W2, b2, z2, 8192, 256, 512, (size_t)0, (size_t)0, (size_t)0,
      MLP_SLOPE, 1);
  // 8. edge dots
  pred_kernel<<<(E * 64 + 255) / 256, 256, 0, stream>>>(z2, ts, out, E);
}

// Round 2
// 804.907 us; speedup vs baseline: 2.2241x; 2.2241x over previous
//
#include <hip/hip_runtime.h>
#include <hip/hip_bf16.h>
#include <cstdint>
#include <cstddef>

#define ALPHA 0.2f
#define MLP_SLOPE 0.01f

typedef short bf16x8 __attribute__((ext_vector_type(8)));
typedef float f32x4 __attribute__((ext_vector_type(4)));
typedef unsigned short ushort_t;

__device__ __forceinline__ float lrelu(float x, float s) { return x > 0.f ? x : x * s; }
__device__ __forceinline__ void fma4(float4& a, float s, const float4& b) {
  a.x = fmaf(s, b.x, a.x); a.y = fmaf(s, b.y, a.y);
  a.z = fmaf(s, b.z, a.z); a.w = fmaf(s, b.w, a.w);
}
__device__ __forceinline__ void add4(float4& a, const float4& b) {
  a.x += b.x; a.y += b.y; a.z += b.z; a.w += b.w;
}
__device__ __forceinline__ void lr4(float4& a, float s) {
  a.x = lrelu(a.x, s); a.y = lrelu(a.y, s); a.z = lrelu(a.z, s); a.w = lrelu(a.w, s);
}
__device__ __forceinline__ ushort_t f2bf(float x) {
  __hip_bfloat16 h = __float2bfloat16(x);
  return *reinterpret_cast<ushort_t*>(&h);
}
__device__ __forceinline__ float bf2f(ushort_t u) {
  union { unsigned int i; float f; } v; v.i = ((unsigned int)u) << 16; return v.f;
}

// ---------------------------------------------------------------------------
// Generic fp32 GEMM: C = act(A[M,K] @ B[K,N] + bias), 128x128 tile, 8x8 micro
// ---------------------------------------------------------------------------
__global__ __launch_bounds__(256) void gemm128(
    const float* __restrict__ A, const float* __restrict__ B,
    const float* __restrict__ bias, float* __restrict__ C,
    int M, int N, int K, size_t asz, size_t bsz, size_t csz,
    float slope, int act)
{
  __shared__ float As[16 * 128];   // [k][m]
  __shared__ float Bs[16 * 128];   // [k][n]
  const float* Ab = A + (size_t)blockIdx.z * asz;
  const float* Bb = B + (size_t)blockIdx.z * bsz;
  float* Cb = C + (size_t)blockIdx.z * csz;
  const int t = threadIdx.x;
  const int bm = blockIdx.y * 128, bn = blockIdx.x * 128;
  const int tx = t & 15, ty = t >> 4;
  float4 acc[8][2];
#pragma unroll
  for (int i = 0; i < 8; ++i) {
    acc[i][0] = make_float4(0.f, 0.f, 0.f, 0.f);
    acc[i][1] = make_float4(0.f, 0.f, 0.f, 0.f);
  }
  for (int k0 = 0; k0 < K; k0 += 16) {
    __syncthreads();
#pragma unroll
    for (int m = 0; m < 2; ++m) {
      int f = m * 256 + t;
      int r = f >> 2, c4 = (f & 3) << 2;
      float4 av = *(const float4*)&Ab[(size_t)(bm + r) * K + k0 + c4];
      As[(c4 + 0) * 128 + r] = av.x;
      As[(c4 + 1) * 128 + r] = av.y;
      As[(c4 + 2) * 128 + r] = av.z;
      As[(c4 + 3) * 128 + r] = av.w;
      int br = f >> 5, bc = (f & 31) << 2;
      *(float4*)&Bs[br * 128 + bc] = *(const float4*)&Bb[(size_t)(k0 + br) * N + bn + bc];
    }
    __syncthreads();
#pragma unroll
    for (int k = 0; k < 16; ++k) {
      float4 a0 = *(const float4*)&As[k * 128 + ty * 8];
      float4 a1 = *(const float4*)&As[k * 128 + ty * 8 + 4];
      float4 b0 = *(const float4*)&Bs[k * 128 + tx * 8];
      float4 b1 = *(const float4*)&Bs[k * 128 + tx * 8 + 4];
      fma4(acc[0][0], a0.x, b0); fma4(acc[0][1], a0.x, b1);
      fma4(acc[1][0], a0.y, b0); fma4(acc[1][1], a0.y, b1);
      fma4(acc[2][0], a0.z, b0); fma4(acc[2][1], a0.z, b1);
      fma4(acc[3][0], a0.w, b0); fma4(acc[3][1], a0.w, b1);
      fma4(acc[4][0], a1.x, b0); fma4(acc[4][1], a1.x, b1);
      fma4(acc[5][0], a1.y, b0); fma4(acc[5][1], a1.y, b1);
      fma4(acc[6][0], a1.z, b0); fma4(acc[6][1], a1.z, b1);
      fma4(acc[7][0], a1.w, b0); fma4(acc[7][1], a1.w, b1);
    }
  }
  float4 bv0 = make_float4(0.f, 0.f, 0.f, 0.f);
  float4 bv1 = bv0;
  if (bias) {
    bv0 = *(const float4*)&bias[bn + tx * 8];
    bv1 = *(const float4*)&bias[bn + tx * 8 + 4];
  }
#pragma unroll
  for (int i = 0; i < 8; ++i) {
    int row = bm + ty * 8 + i;
    float4 v0 = acc[i][0], v1 = acc[i][1];
    add4(v0, bv0); add4(v1, bv1);
    if (act) { lr4(v0, slope); lr4(v1, slope); }
    *(float4*)&Cb[(size_t)row * N + bn + tx * 8] = v0;
    *(float4*)&Cb[(size_t)row * N + bn + tx * 8 + 4] = v1;
  }
}

// ---------------------------------------------------------------------------
// s1/s2: per-row dots of h with a1/a2 (one wave per row, both heads)
// ---------------------------------------------------------------------------
__global__ __launch_bounds__(256) void s_kernel(
    const float* __restrict__ hbuf, const float* __restrict__ a1,
    const float* __restrict__ a2, float* __restrict__ s1, float* __restrict__ s2)
{
  const int gw = (blockIdx.x * 256 + threadIdx.x) >> 6;   // row 0..8191
  const int lane = threadIdx.x & 63;
#pragma unroll
  for (int hh = 0; hh < 2; ++hh) {
    float4 hv = ((const float4*)(hbuf + ((size_t)hh * 8192 + gw) * 256))[lane];
    float4 a1v = ((const float4*)(a1 + hh * 256))[lane];
    float4 a2v = ((const float4*)(a2 + hh * 256))[lane];
    float p1 = hv.x * a1v.x + hv.y * a1v.y + hv.z * a1v.z + hv.w * a1v.w;
    float p2 = hv.x * a2v.x + hv.y * a2v.y + hv.z * a2v.z + hv.w * a2v.w;
    for (int off = 32; off > 0; off >>= 1) {
      p1 += __shfl_xor(p1, off);
      p2 += __shfl_xor(p2, off);
    }
    if (lane == 0) {
      s1[hh * 8192 + gw] = p1;
      s2[hh * 8192 + gw] = p2;
    }
  }
}

// ---------------------------------------------------------------------------
// Transpose + bf16 convert: hbuf [head][j][c] f32 -> Hbt [head][c][j] bf16
// ---------------------------------------------------------------------------
__global__ __launch_bounds__(256) void h2bf(
    const float* __restrict__ hbuf, ushort_t* __restrict__ Hbt)
{
  __shared__ float tile[64][65];
  const int t = threadIdx.x;
  const int j0 = blockIdx.x * 64;
  const int c0 = blockIdx.y * 64;
  const int head = blockIdx.z;
#pragma unroll
  for (int it = 0; it < 4; ++it) {
    int f = it * 256 + t;
    int jr = f >> 4, c4 = (f & 15) * 4;
    float4 v = *(const float4*)&hbuf[((size_t)head * 8192 + j0 + jr) * 256 + c0 + c4];
    tile[jr][c4 + 0] = v.x; tile[jr][c4 + 1] = v.y;
    tile[jr][c4 + 2] = v.z; tile[jr][c4 + 3] = v.w;
  }
  __syncthreads();
#pragma unroll
  for (int it = 0; it < 4; ++it) {
    int f = it * 256 + t;
    int cr = f >> 4, j4 = (f & 15) * 4;
    ushort4 u;
    u.x = f2bf(tile[j4 + 0][cr]);
    u.y = f2bf(tile[j4 + 1][cr]);
    u.z = f2bf(tile[j4 + 2][cr]);
    u.w = f2bf(tile[j4 + 3][cr]);
    *(ushort4*)&Hbt[((size_t)head * 256 + c0 + cr) * 8192 + j0 + j4] = u;
  }
}

// ---------------------------------------------------------------------------
// MFMA attention: O[i,c] = sum_j w[i,j] h[j,c], w generated on the fly.
// Block: 64 rows x 256 cols x 2 heads, K-slice 2048 (js 0..3), K-step 32.
// 4 waves: wave = (head, n-half of 128). adj read once, shared by heads.
// ---------------------------------------------------------------------------
__global__ __launch_bounds__(256, 2) void attn_mfma(
    const ushort_t* __restrict__ Hbt, const float* __restrict__ s1g,
    const float* __restrict__ s2g, const int* __restrict__ adj,
    ushort_t* __restrict__ pacc, float* __restrict__ pl)
{
  __shared__ ushort_t Wlds[2][64][40];    // [head][m][k], pad 40
  __shared__ ushort_t Hlds[2][256][40];   // [head][n][k], pad 40
  const int t = threadIdx.x;
  const int i0 = blockIdx.x * 64;
  const int js = blockIdx.y;
  const int kbase = js * 2048;
  // W-gen mapping: thread covers (row wr, k-cols wc..wc+8)
  const int wr = t >> 2;
  const int wc = (t & 3) * 8;
  const float s1v0 = s1g[i0 + wr];
  const float s1v1 = s1g[8192 + i0 + wr];
  // MFMA mapping
  const int wave = t >> 6;
  const int head = wave >> 1;
  const int n0 = (wave & 1) * 128;
  const int l16 = t & 15;
  const int quad = (t >> 4) & 3;
  f32x4 acc[4][8];
#pragma unroll
  for (int m = 0; m < 4; ++m)
#pragma unroll
    for (int n = 0; n < 8; ++n) acc[m][n] = (f32x4){0.f, 0.f, 0.f, 0.f};
  float rs0 = 0.f, rs1 = 0.f;

  for (int kt = 0; kt < 64; ++kt) {
    const int k0 = kbase + kt * 32;
    __syncthreads();
    // ---- stage H tiles: 2 heads x 256 n-rows x 32 k (bf16) ----
#pragma unroll
    for (int q = 0; q < 8; ++q) {
      int f = q * 256 + t;
      int hh = f >> 10, rem = f & 1023, c = rem >> 2, ch = rem & 3;
      uint4 v = *(const uint4*)&Hbt[((size_t)hh * 256 + c) * 8192 + k0 + ch * 8];
      *(uint4*)&Hlds[hh][c][ch * 8] = v;
    }
    // ---- generate W tiles (both heads) from one adj read ----
    {
      const int4* ap = (const int4*)(adj + (size_t)(i0 + wr) * 8192 + k0 + wc);
      int4 av0 = ap[0], av1 = ap[1];
      float4 sa0 = *(const float4*)&s2g[k0 + wc];
      float4 sb0 = *(const float4*)&s2g[k0 + wc + 4];
      float4 sa1 = *(const float4*)&s2g[8192 + k0 + wc];
      float4 sb1 = *(const float4*)&s2g[8192 + k0 + wc + 4];
      int am[8] = {av0.x, av0.y, av0.z, av0.w, av1.x, av1.y, av1.z, av1.w};
      float s20[8] = {sa0.x, sa0.y, sa0.z, sa0.w, sb0.x, sb0.y, sb0.z, sb0.w};
      float s21[8] = {sa1.x, sa1.y, sa1.z, sa1.w, sb1.x, sb1.y, sb1.z, sb1.w};
      ushort_t wb0[8], wb1[8];
#pragma unroll
      for (int e = 0; e < 8; ++e) {
        float e0 = s1v0 + s20[e];
        float e1 = s1v1 + s21[e];
        e0 = fmaxf(e0, 0.f) + ALPHA * fminf(e0, 0.f);
        e1 = fmaxf(e1, 0.f) + ALPHA * fminf(e1, 0.f);
        float w0 = am[e] > 0 ? __expf(e0) : 0.f;
        float w1 = am[e] > 0 ? __expf(e1) : 0.f;
        rs0 += w0; rs1 += w1;
        wb0[e] = f2bf(w0); wb1[e] = f2bf(w1);
      }
      *(uint4*)&Wlds[0][wr][wc] = *(uint4*)wb0;
      *(uint4*)&Wlds[1][wr][wc] = *(uint4*)wb1;
    }
    __syncthreads();
    // ---- fragments + MFMA ----
    bf16x8 Af[4], Bf[8];
#pragma unroll
    for (int mt = 0; mt < 4; ++mt)
      Af[mt] = *(const bf16x8*)&Wlds[head][mt * 16 + l16][quad * 8];
#pragma unroll
    for (int nt = 0; nt < 8; ++nt)
      Bf[nt] = *(const bf16x8*)&Hlds[head][n0 + nt * 16 + l16][quad * 8];
#pragma unroll
    for (int mt = 0; mt < 4; ++mt)
#pragma unroll
      for (int nt = 0; nt < 8; ++nt)
        acc[mt][nt] = __builtin_amdgcn_mfma_f32_16x16x32_bf16(
            Af[mt], Bf[nt], acc[mt][nt], 0, 0, 0);
  }
  // ---- denominators: reduce 4 lanes per row ----
  rs0 += __shfl_xor(rs0, 1); rs0 += __shfl_xor(rs0, 2);
  rs1 += __shfl_xor(rs1, 1); rs1 += __shfl_xor(rs1, 2);
  if ((t & 3) == 0) {
    pl[((size_t)js * 2 + 0) * 8192 + i0 + wr] = rs0;
    pl[((size_t)js * 2 + 1) * 8192 + i0 + wr] = rs1;
  }
  // ---- store bf16 partial numerators ----
#pragma unroll
  for (int mt = 0; mt < 4; ++mt)
#pragma unroll
    for (int nt = 0; nt < 8; ++nt)
#pragma unroll
      for (int rg = 0; rg < 4; ++rg) {
        int row = i0 + mt * 16 + quad * 4 + rg;
        int col = n0 + nt * 16 + l16;
        pacc[(((size_t)js * 2 + head) * 8192 + row) * 256 + col] =
            f2bf(acc[mt][nt][rg]);
      }
}

// ---------------------------------------------------------------------------
// Finalize: sum 4 j-parts, /l, leaky_relu, l2-normalize, +bias, head-mean
// ---------------------------------------------------------------------------
__global__ __launch_bounds__(256) void attn_finalize(
    const ushort_t* __restrict__ pacc, const float* __restrict__ pl,
    const float* __restrict__ bg, float* __restrict__ embed)
{
  __shared__ float red[256];
  const int r = blockIdx.x;
  const int t = threadIdx.x;
  float o[2], nrm[2];
#pragma unroll
  for (int hh = 0; hh < 2; ++hh) {
    float num = 0.f, l = 0.f;
#pragma unroll
    for (int js = 0; js < 4; ++js) {
      num += bf2f(pacc[(((size_t)js * 2 + hh) * 8192 + r) * 256 + t]);
      l += pl[((size_t)js * 2 + hh) * 8192 + r];
    }
    o[hh] = lrelu(num / l, ALPHA);
  }
  for (int hh = 0; hh < 2; ++hh) {
    __syncthreads();
    red[t] = o[hh] * o[hh];
    __syncthreads();
    for (int s = 128; s > 0; s >>= 1) {
      if (t < s) red[t] += red[t + s];
      __syncthreads();
    }
    nrm[hh] = fmaxf(sqrtf(red[0]), 1e-12f);
  }
  embed[(size_t)r * 768 + 512 + t] =
      0.5f * (o[0] / nrm[0] + bg[t] + o[1] / nrm[1] + bg[256 + t]);
}

// ---------------------------------------------------------------------------
__global__ __launch_bounds__(256) void copy_llm(
    const float* __restrict__ llm, float* __restrict__ embed)
{
  int idx = blockIdx.x * 256 + threadIdx.x;   // float4 id over 8192x512
  int r = idx >> 7, c = idx & 127;
  ((float4*)embed)[(size_t)r * 192 + c] = ((const float4*)llm)[idx];
}

// ---------------------------------------------------------------------------
__global__ __launch_bounds__(256) void pred_kernel(
    const float* __restrict__ z2, const int* __restrict__ ts,
    float* __restrict__ out, int E)
{
  const int gw = (blockIdx.x * 256 + threadIdx.x) >> 6;
  const int lane = threadIdx.x & 63;
  if (gw >= E) return;
  const int a = ts[gw * 2], b = ts[gw * 2 + 1];
  float4 va = ((const float4*)(z2 + (size_t)a * 256))[lane];
  float4 vb = ((const float4*)(z2 + (size_t)b * 256))[lane];
  float p = va.x * vb.x + va.y * vb.y + va.z * vb.z + va.w * vb.w;
  for (int off = 32; off > 0; off >>= 1) p += __shfl_xor(p, off);
  if (lane == 0) out[gw] = p;
}

// ---------------------------------------------------------------------------
extern "C" void kernel_launch(void* const* d_in, const int* in_sizes, int n_in,
                              void* d_out, int out_size, void* d_ws, size_t ws_size,
                              hipStream_t stream) {
  const float* x   = (const float*)d_in[0];
  const int*   adj = (const int*)d_in[1];
  const int*   ts  = (const int*)d_in[2];
  const float* llm = (const float*)d_in[3];
  const float* Wg  = (const float*)d_in[4];
  const float* a1  = (const float*)d_in[5];
  const float* a2  = (const float*)d_in[6];
  const float* bg  = (const float*)d_in[7];
  const float* W1  = (const float*)d_in[8];
  const float* b1  = (const float*)d_in[9];
  const float* W2  = (const float*)d_in[10];
  const float* b2  = (const float*)d_in[11];
  float* out = (float*)d_out;
  float* ws  = (float*)d_ws;
  const int E = in_sizes[2] / 2;

  // workspace layout (float words); embed overlays hbuf+Hbt (dead by then)
  float*    hbuf  = ws;                         // [0, 4194304)
  ushort_t* Hbt   = (ushort_t*)(ws + 4194304);  // 4,194,304 us = [4194304, 6291456)
  float*    s1    = ws + 6291456;               // 16384
  float*    s2    = ws + 6307840;               // 16384
  float*    pl    = ws + 6324224;               // 4*2*8192 = 65536
  ushort_t* pacc  = (ushort_t*)(ws + 6389760);  // 16,777,216 us = [6389760, 14778368)
  float*    embed = ws;                         // 8192*768 = [0, 6291456)  (overlay)
  float*    z1    = ws + 14778368;              // 8192*512
  float*    z2    = ws + 18972672;              // 8192*256  (end 21069824 ~ 84 MB)

  // 1. h[head] = x @ Wg[head]   (fp32)
  gemm128<<<dim3(2, 64, 2), 256, 0, stream>>>(
      x, Wg, nullptr, hbuf, 8192, 256, 512,
      (size_t)0, (size_t)512 * 256, (size_t)8192 * 256, 0.f, 0);
  // 2. s1/s2 row dots
  s_kernel<<<2048, 256, 0, stream>>>(hbuf, a1, a2, s1, s2);
  // 3. transpose + bf16 convert h
  h2bf<<<dim3(128, 4, 2), 256, 0, stream>>>(hbuf, Hbt);
  // 4. MFMA attention partials
  attn_mfma<<<dim3(128, 4), 256, 0, stream>>>(Hbt, s1, s2, adj, pacc, pl);
  // 5. embed[:, :512] = llm_emb
  copy_llm<<<4096, 256, 0, stream>>>(llm, embed);
  // 6. embed[:, 512:] = attention epilogue
  attn_finalize<<<8192, 256, 0, stream>>>(pacc, pl, bg, embed);
  // 7. z1 = LR(embed @ W1 + b1)
  gemm128<<<dim3(4, 64, 1), 256, 0, stream>>>(
      embed, W1, b1, z1, 8192, 512, 768, (size_t)0, (size_t)0, (size_t)0,
      MLP_SLOPE, 1);
  // 8. z2 = LR(z1 @ W2 + b2)
  gemm128<<<dim3(2, 64, 1), 256, 0, stream>>>(
      z1, W2, b2, z2, 8192, 256, 512, (size_t)0, (size_t)0, (size_t)0,
      MLP_SLOPE, 1);
  // 9. edge dots
  pred_kernel<<<(E * 64 + 255) / 256, 256, 0, stream>>>(z2, ts, out, E);
}

// Round 3
// 667.765 us; speedup vs baseline: 2.6808x; 1.2054x over previous
//
#include <hip/hip_runtime.h>
#include <hip/hip_bf16.h>
#include <cstdint>
#include <cstddef>

#define ALPHA 0.2f
#define MLP_SLOPE 0.01f

typedef short bf16x8 __attribute__((ext_vector_type(8)));
typedef float f32x4 __attribute__((ext_vector_type(4)));
typedef unsigned short ushort_t;

__device__ __forceinline__ float lrelu(float x, float s) { return x > 0.f ? x : x * s; }
__device__ __forceinline__ ushort_t f2bf(float x) {
  __hip_bfloat16 h = __float2bfloat16(x);
  return *reinterpret_cast<ushort_t*>(&h);
}
__device__ __forceinline__ float bf2f(ushort_t u) {
  union { unsigned int i; float f; } v; v.i = ((unsigned int)u) << 16; return v.f;
}

// ---------------------------------------------------------------------------
// split fp32 -> (hi, lo) bf16, elementwise (4 elems/thread)
// ---------------------------------------------------------------------------
__global__ __launch_bounds__(256) void split_f(
    const float* __restrict__ in, ushort_t* __restrict__ hi,
    ushort_t* __restrict__ lo)
{
  int idx = blockIdx.x * 256 + threadIdx.x;
  float4 v = ((const float4*)in)[idx];
  ushort4 h, l;
  h.x = f2bf(v.x); l.x = f2bf(v.x - bf2f(h.x));
  h.y = f2bf(v.y); l.y = f2bf(v.y - bf2f(h.y));
  h.z = f2bf(v.z); l.z = f2bf(v.z - bf2f(h.z));
  h.w = f2bf(v.w); l.w = f2bf(v.w - bf2f(h.w));
  ((ushort4*)hi)[idx] = h;
  ((ushort4*)lo)[idx] = l;
}

// ---------------------------------------------------------------------------
// transpose + split: W[K,N] -> T[N,K] hi/lo bf16 (batch via blockIdx.y)
// ---------------------------------------------------------------------------
__global__ __launch_bounds__(256) void split_t(
    const float* __restrict__ W, ushort_t* __restrict__ Thi,
    ushort_t* __restrict__ Tlo, int K, int N)
{
  int idx = blockIdx.x * 256 + threadIdx.x;
  if (idx >= K * N) return;
  int k = idx / N, n = idx - k * N;
  size_t b = (size_t)blockIdx.y * K * N;
  float v = W[b + idx];
  ushort_t h = f2bf(v);
  size_t o = b + (size_t)n * K + k;
  Thi[o] = h; Tlo[o] = f2bf(v - bf2f(h));
}

// ---------------------------------------------------------------------------
// Split-precision bf16 MFMA GEMM: C = act(A[M,K] @ Bt[N,K]^T + bias)
// A,Bt as hi/lo bf16 pairs; 3-pass accumulation (hi*hi + hi*lo + lo*hi).
// Block 128x128, 4 waves of 64x64, k-step 32. batch via blockIdx.z.
// ---------------------------------------------------------------------------
__global__ __launch_bounds__(256, 2) void gemm_bf16s(
    const ushort_t* __restrict__ Ahi, const ushort_t* __restrict__ Alo,
    const ushort_t* __restrict__ Bthi, const ushort_t* __restrict__ Btlo,
    const float* __restrict__ bias, float* __restrict__ Cf,
    ushort_t* __restrict__ Chi, ushort_t* __restrict__ Clo,
    int M, int N, int K, float slope, int act)
{
  __shared__ ushort_t Ah[128][40], Al[128][40], Bh[128][40], Bl[128][40];
  const size_t boff = (size_t)blockIdx.z * N * K;
  const size_t coff = (size_t)blockIdx.z * M * N;
  const int t = threadIdx.x;
  const int m0 = blockIdx.y * 128, n0 = blockIdx.x * 128;
  const int srow = t >> 1, spart = (t & 1) * 16;
  const int wave = t >> 6;
  const int wm = (wave >> 1) * 64, wn = (wave & 1) * 64;
  const int l16 = t & 15, quad = (t >> 4) & 3;
  f32x4 acc[4][4];
#pragma unroll
  for (int i = 0; i < 4; ++i)
#pragma unroll
    for (int j = 0; j < 4; ++j) acc[i][j] = (f32x4){0.f, 0.f, 0.f, 0.f};

  for (int k0 = 0; k0 < K; k0 += 32) {
    __syncthreads();
    const size_t abase = (size_t)(m0 + srow) * K + k0 + spart;
    const size_t bbase = boff + (size_t)(n0 + srow) * K + k0 + spart;
    *(uint4*)&Ah[srow][spart]     = *(const uint4*)&Ahi[abase];
    *(uint4*)&Ah[srow][spart + 8] = *(const uint4*)&Ahi[abase + 8];
    *(uint4*)&Al[srow][spart]     = *(const uint4*)&Alo[abase];
    *(uint4*)&Al[srow][spart + 8] = *(const uint4*)&Alo[abase + 8];
    *(uint4*)&Bh[srow][spart]     = *(const uint4*)&Bthi[bbase];
    *(uint4*)&Bh[srow][spart + 8] = *(const uint4*)&Bthi[bbase + 8];
    *(uint4*)&Bl[srow][spart]     = *(const uint4*)&Btlo[bbase];
    *(uint4*)&Bl[srow][spart + 8] = *(const uint4*)&Btlo[bbase + 8];
    __syncthreads();
    bf16x8 afh[4], afl[4], bfh[4], bfl[4];
#pragma unroll
    for (int mt = 0; mt < 4; ++mt) {
      afh[mt] = *(const bf16x8*)&Ah[wm + mt * 16 + l16][quad * 8];
      afl[mt] = *(const bf16x8*)&Al[wm + mt * 16 + l16][quad * 8];
    }
#pragma unroll
    for (int nt = 0; nt < 4; ++nt) {
      bfh[nt] = *(const bf16x8*)&Bh[wn + nt * 16 + l16][quad * 8];
      bfl[nt] = *(const bf16x8*)&Bl[wn + nt * 16 + l16][quad * 8];
    }
#pragma unroll
    for (int mt = 0; mt < 4; ++mt)
#pragma unroll
      for (int nt = 0; nt < 4; ++nt) {
        acc[mt][nt] = __builtin_amdgcn_mfma_f32_16x16x32_bf16(afh[mt], bfh[nt], acc[mt][nt], 0, 0, 0);
        acc[mt][nt] = __builtin_amdgcn_mfma_f32_16x16x32_bf16(afh[mt], bfl[nt], acc[mt][nt], 0, 0, 0);
        acc[mt][nt] = __builtin_amdgcn_mfma_f32_16x16x32_bf16(afl[mt], bfh[nt], acc[mt][nt], 0, 0, 0);
      }
  }
#pragma unroll
  for (int mt = 0; mt < 4; ++mt)
#pragma unroll
    for (int nt = 0; nt < 4; ++nt)
#pragma unroll
      for (int rg = 0; rg < 4; ++rg) {
        int m = m0 + wm + mt * 16 + quad * 4 + rg;
        int n = n0 + wn + nt * 16 + l16;
        float v = acc[mt][nt][rg];
        if (bias) v += bias[n];
        if (act) v = lrelu(v, slope);
        size_t o = coff + (size_t)m * N + n;
        if (Cf) Cf[o] = v;
        if (Chi) {
          ushort_t h = f2bf(v);
          Chi[o] = h; Clo[o] = f2bf(v - bf2f(h));
        }
      }
}

// ---------------------------------------------------------------------------
// s1/s2: per-row dots of h with a1/a2 (one wave per row, both heads)
// ---------------------------------------------------------------------------
__global__ __launch_bounds__(256) void s_kernel(
    const float* __restrict__ hbuf, const float* __restrict__ a1,
    const float* __restrict__ a2, float* __restrict__ s1, float* __restrict__ s2)
{
  const int gw = (blockIdx.x * 256 + threadIdx.x) >> 6;
  const int lane = threadIdx.x & 63;
#pragma unroll
  for (int hh = 0; hh < 2; ++hh) {
    float4 hv = ((const float4*)(hbuf + ((size_t)hh * 8192 + gw) * 256))[lane];
    float4 a1v = ((const float4*)(a1 + hh * 256))[lane];
    float4 a2v = ((const float4*)(a2 + hh * 256))[lane];
    float p1 = hv.x * a1v.x + hv.y * a1v.y + hv.z * a1v.z + hv.w * a1v.w;
    float p2 = hv.x * a2v.x + hv.y * a2v.y + hv.z * a2v.z + hv.w * a2v.w;
    for (int off = 32; off > 0; off >>= 1) {
      p1 += __shfl_xor(p1, off);
      p2 += __shfl_xor(p2, off);
    }
    if (lane == 0) {
      s1[hh * 8192 + gw] = p1;
      s2[hh * 8192 + gw] = p2;
    }
  }
}

// ---------------------------------------------------------------------------
// Pack h (fp32 [head][j][c]) into MFMA B-fragment order:
// Bpack[(((head*256 + kblk)*16 + ntile)*64 + lane)*8 + e]
//   = bf16(h[head][kblk*32 + (lane>>4)*8 + e][ntile*16 + (lane&15)])
// ---------------------------------------------------------------------------
__global__ __launch_bounds__(256) void h_pack(
    const float* __restrict__ hbuf, ushort_t* __restrict__ Bpack)
{
  int gid = blockIdx.x * 256 + threadIdx.x;   // 0 .. 524287
  int lane = gid & 63;
  int ntile = (gid >> 6) & 15;
  int kblk = (gid >> 10) & 255;
  int head = gid >> 18;
  int c = ntile * 16 + (lane & 15);
  int jb = kblk * 32 + (lane >> 4) * 8;
  ushort_t o[8];
#pragma unroll
  for (int e = 0; e < 8; ++e)
    o[e] = f2bf(hbuf[((size_t)head * 8192 + jb + e) * 256 + c]);
  *(uint4*)&Bpack[(size_t)gid * 8] = *(uint4*)o;
}

// ---------------------------------------------------------------------------
// MFMA attention v2: no H staging (B-frags direct from L2-resident Bpack),
// W generated into A-frag-ordered LDS, double-buffered, 1 barrier/step,
// adj/s2 prefetched one step ahead. Block: 64 rows x 256 cols x 2 heads,
// 4 waves = (head, n-half). Grid (128, 4): js = k-slice of 2048.
// ---------------------------------------------------------------------------
__global__ __launch_bounds__(256, 2) void attn_mfma2(
    const ushort_t* __restrict__ Bpack, const float* __restrict__ s1g,
    const float* __restrict__ s2g, const int* __restrict__ adj,
    ushort_t* __restrict__ pacc, float* __restrict__ pl)
{
  __shared__ ushort_t Wlds[2][2][4][64][8];   // [buf][head][mt][lane][8]
  const int t = threadIdx.x;
  const int i0 = blockIdx.x * 64;
  const int js = blockIdx.y;
  const int kbase = js * 2048;
  // generator mapping: row wr (0..63), k-octet kq (0..3)
  const int wr = t >> 2, kq = t & 3;
  const int glane = kq * 16 + (wr & 15);
  const int gmt = wr >> 4;
  const float s1v0 = s1g[i0 + wr];
  const float s1v1 = s1g[8192 + i0 + wr];
  // consumer mapping
  const int wave = t >> 6, head = wave >> 1, nh = wave & 1;
  const int l16 = t & 15, quad = (t >> 4) & 3;
  const int l63 = t & 63;
  f32x4 acc[4][8];
#pragma unroll
  for (int m = 0; m < 4; ++m)
#pragma unroll
    for (int n = 0; n < 8; ++n) acc[m][n] = (f32x4){0.f, 0.f, 0.f, 0.f};
  float rs0 = 0.f, rs1 = 0.f;

  const int* arow = adj + (size_t)(i0 + wr) * 8192;
  // prefetch step 0
  int4 pa0, pa1;
  float4 p20a, p20b, p21a, p21b;
  {
    const int kk = kbase + kq * 8;
    pa0 = *(const int4*)&arow[kk];
    pa1 = *(const int4*)&arow[kk + 4];
    p20a = *(const float4*)&s2g[kk];
    p20b = *(const float4*)&s2g[kk + 4];
    p21a = *(const float4*)&s2g[8192 + kk];
    p21b = *(const float4*)&s2g[8192 + kk + 4];
  }
  for (int kt = 0; kt < 64; ++kt) {
    const int buf = kt & 1;
    // ---- generate W for this step from prefetched regs ----
    {
      int am[8] = {pa0.x, pa0.y, pa0.z, pa0.w, pa1.x, pa1.y, pa1.z, pa1.w};
      float s20[8] = {p20a.x, p20a.y, p20a.z, p20a.w, p20b.x, p20b.y, p20b.z, p20b.w};
      float s21[8] = {p21a.x, p21a.y, p21a.z, p21a.w, p21b.x, p21b.y, p21b.z, p21b.w};
      ushort_t w0[8], w1[8];
#pragma unroll
      for (int e = 0; e < 8; ++e) {
        float e0 = s1v0 + s20[e];
        float e1 = s1v1 + s21[e];
        e0 = fmaxf(e0, 0.f) + ALPHA * fminf(e0, 0.f);
        e1 = fmaxf(e1, 0.f) + ALPHA * fminf(e1, 0.f);
        float v0 = am[e] > 0 ? __expf(e0) : 0.f;
        float v1 = am[e] > 0 ? __expf(e1) : 0.f;
        rs0 += v0; rs1 += v1;
        w0[e] = f2bf(v0); w1[e] = f2bf(v1);
      }
      *(uint4*)&Wlds[buf][0][gmt][glane][0] = *(uint4*)w0;
      *(uint4*)&Wlds[buf][1][gmt][glane][0] = *(uint4*)w1;
    }
    // ---- prefetch next step ----
    if (kt < 63) {
      const int kk = kbase + (kt + 1) * 32 + kq * 8;
      pa0 = *(const int4*)&arow[kk];
      pa1 = *(const int4*)&arow[kk + 4];
      p20a = *(const float4*)&s2g[kk];
      p20b = *(const float4*)&s2g[kk + 4];
      p21a = *(const float4*)&s2g[8192 + kk];
      p21b = *(const float4*)&s2g[8192 + kk + 4];
    }
    __syncthreads();
    // ---- fragments + MFMA ----
    const int kblk = js * 64 + kt;
    const ushort_t* bbase =
        Bpack + ((((size_t)head * 256 + kblk) * 16 + nh * 8) * 64 + l63) * 8;
    bf16x8 Af[4], Bf[8];
#pragma unroll
    for (int mt = 0; mt < 4; ++mt)
      Af[mt] = *(const bf16x8*)&Wlds[buf][head][mt][l63][0];
#pragma unroll
    for (int nt = 0; nt < 8; ++nt)
      Bf[nt] = *(const bf16x8*)&bbase[nt * 512];
#pragma unroll
    for (int mt = 0; mt < 4; ++mt)
#pragma unroll
      for (int nt = 0; nt < 8; ++nt)
        acc[mt][nt] = __builtin_amdgcn_mfma_f32_16x16x32_bf16(
            Af[mt], Bf[nt], acc[mt][nt], 0, 0, 0);
  }
  // ---- denominators: sum across the 4 kq-threads of each row ----
  rs0 += __shfl_xor(rs0, 1); rs0 += __shfl_xor(rs0, 2);
  rs1 += __shfl_xor(rs1, 1); rs1 += __shfl_xor(rs1, 2);
  if (kq == 0) {
    pl[((size_t)js * 2 + 0) * 8192 + i0 + wr] = rs0;
    pl[((size_t)js * 2 + 1) * 8192 + i0 + wr] = rs1;
  }
  // ---- store bf16 partial numerators ----
  const int n0 = nh * 128;
#pragma unroll
  for (int mt = 0; mt < 4; ++mt)
#pragma unroll
    for (int nt = 0; nt < 8; ++nt)
#pragma unroll
      for (int rg = 0; rg < 4; ++rg) {
        int row = i0 + mt * 16 + quad * 4 + rg;
        int col = n0 + nt * 16 + l16;
        pacc[(((size_t)js * 2 + head) * 8192 + row) * 256 + col] =
            f2bf(acc[mt][nt][rg]);
      }
}

// ---------------------------------------------------------------------------
// Finalize: sum 4 j-parts, /l, leaky_relu, l2-normalize, +bias, head-mean
// ---------------------------------------------------------------------------
__global__ __launch_bounds__(256) void attn_finalize(
    const ushort_t* __restrict__ pacc, const float* __restrict__ pl,
    const float* __restrict__ bg, float* __restrict__ embed)
{
  __shared__ float red[256];
  const int r = blockIdx.x;
  const int t = threadIdx.x;
  float o[2], nrm[2];
#pragma unroll
  for (int hh = 0; hh < 2; ++hh) {
    float num = 0.f, l = 0.f;
#pragma unroll
    for (int js = 0; js < 4; ++js) {
      num += bf2f(pacc[(((size_t)js * 2 + hh) * 8192 + r) * 256 + t]);
      l += pl[((size_t)js * 2 + hh) * 8192 + r];
    }
    o[hh] = lrelu(num / l, ALPHA);
  }
  for (int hh = 0; hh < 2; ++hh) {
    __syncthreads();
    red[t] = o[hh] * o[hh];
    __syncthreads();
    for (int s = 128; s > 0; s >>= 1) {
      if (t < s) red[t] += red[t + s];
      __syncthreads();
    }
    nrm[hh] = fmaxf(sqrtf(red[0]), 1e-12f);
  }
  embed[(size_t)r * 768 + 512 + t] =
      0.5f * (o[0] / nrm[0] + bg[t] + o[1] / nrm[1] + bg[256 + t]);
}

// ---------------------------------------------------------------------------
__global__ __launch_bounds__(256) void copy_llm(
    const float* __restrict__ llm, float* __restrict__ embed)
{
  int idx = blockIdx.x * 256 + threadIdx.x;
  int r = idx >> 7, c = idx & 127;
  ((float4*)embed)[(size_t)r * 192 + c] = ((const float4*)llm)[idx];
}

// ---------------------------------------------------------------------------
__global__ __launch_bounds__(256) void pred_kernel(
    const float* __restrict__ z2, const int* __restrict__ ts,
    float* __restrict__ out, int E)
{
  const int gw = (blockIdx.x * 256 + threadIdx.x) >> 6;
  const int lane = threadIdx.x & 63;
  if (gw >= E) return;
  const int a = ts[gw * 2], b = ts[gw * 2 + 1];
  float4 va = ((const float4*)(z2 + (size_t)a * 256))[lane];
  float4 vb = ((const float4*)(z2 + (size_t)b * 256))[lane];
  float p = va.x * vb.x + va.y * vb.y + va.z * vb.z + va.w * vb.w;
  for (int off = 32; off > 0; off >>= 1) p += __shfl_xor(p, off);
  if (lane == 0) out[gw] = p;
}

// ---------------------------------------------------------------------------
extern "C" void kernel_launch(void* const* d_in, const int* in_sizes, int n_in,
                              void* d_out, int out_size, void* d_ws, size_t ws_size,
                              hipStream_t stream) {
  const float* x   = (const float*)d_in[0];
  const int*   adj = (const int*)d_in[1];
  const int*   ts  = (const int*)d_in[2];
  const float* llm = (const float*)d_in[3];
  const float* Wg  = (const float*)d_in[4];
  const float* a1  = (const float*)d_in[5];
  const float* a2  = (const float*)d_in[6];
  const float* bg  = (const float*)d_in[7];
  const float* W1  = (const float*)d_in[8];
  const float* b1  = (const float*)d_in[9];
  const float* W2  = (const float*)d_in[10];
  const float* b2  = (const float*)d_in[11];
  float* out = (float*)d_out;
  float* ws  = (float*)d_ws;
  const int E = in_sizes[2] / 2;

  // ---- workspace layout (float words), with lifetime overlays ----
  float*    hbuf  = ws;                             // [0, 4194304)
  ushort_t* Bpack = (ushort_t*)(ws + 4194304);      // 8MB bf16 [4194304, 6291456)
  float*    embed = ws;                             // overlay hbuf+Bpack [0, 6291456)
  ushort_t* xhi   = (ushort_t*)(ws + 6291456);      // [6291456, 8388608)
  ushort_t* xlo   = (ushort_t*)(ws + 8388608);      // [8388608, 10485760)
  ushort_t* z1hi  = xhi;                            // overlay (x dead after h-GEMM)
  ushort_t* z1lo  = xlo;
  float*    s1    = ws + 10485760;                  // +16384
  float*    s2    = ws + 10502144;                  // +16384
  float*    pl    = ws + 10518528;                  // +65536 -> 10584064
  ushort_t* pacc  = (ushort_t*)(ws + 10584064);     // [10584064, 18972672)
  ushort_t* ehi   = (ushort_t*)(ws + 10584064);     // overlay pacc (dead after finalize)
  ushort_t* elo   = (ushort_t*)(ws + 13729792);
  float*    z2    = ws + 16875520;                  // [16875520, 18972672)
  ushort_t* wgthi = (ushort_t*)(ws + 18972672);     // 2*256*512 bf16 = 131072 w
  ushort_t* wgtlo = (ushort_t*)(ws + 19103744);
  ushort_t* w1thi = (ushort_t*)(ws + 19234816);     // 512*768 = 196608 w
  ushort_t* w1tlo = (ushort_t*)(ws + 19431424);
  ushort_t* w2thi = (ushort_t*)(ws + 19628032);     // 256*512 = 65536 w
  ushort_t* w2tlo = (ushort_t*)(ws + 19693568);     // end 19759104 w (~79 MB)

  // 1. splits / transposes
  split_f<<<4096, 256, 0, stream>>>(x, xhi, xlo);                       // 8192x512
  split_t<<<dim3(512, 2), 256, 0, stream>>>(Wg, wgthi, wgtlo, 512, 256);
  split_t<<<dim3(1536, 1), 256, 0, stream>>>(W1, w1thi, w1tlo, 768, 512);
  split_t<<<dim3(512, 1), 256, 0, stream>>>(W2, w2thi, w2tlo, 512, 256);
  // 2. h[head] = x @ Wg[head]  (split bf16, fp32 out)
  gemm_bf16s<<<dim3(2, 64, 2), 256, 0, stream>>>(
      xhi, xlo, wgthi, wgtlo, nullptr, hbuf, nullptr, nullptr,
      8192, 256, 512, 0.f, 0);
  // 3. s1/s2 row dots
  s_kernel<<<2048, 256, 0, stream>>>(hbuf, a1, a2, s1, s2);
  // 4. pack h into B-fragment order
  h_pack<<<2048, 256, 0, stream>>>(hbuf, Bpack);
  // 5. MFMA attention partials
  attn_mfma2<<<dim3(128, 4), 256, 0, stream>>>(Bpack, s1, s2, adj, pacc, pl);
  // 6. embed[:, :512] = llm_emb   (hbuf/Bpack dead now)
  copy_llm<<<4096, 256, 0, stream>>>(llm, embed);
  // 7. embed[:, 512:] = attention epilogue
  attn_finalize<<<8192, 256, 0, stream>>>(pacc, pl, bg, embed);
  // 8. split embed (pacc dead now)
  split_f<<<6144, 256, 0, stream>>>(embed, ehi, elo);                   // 8192x768
  // 9. z1 = LR(embed @ W1 + b1) -> hi/lo bf16 directly
  gemm_bf16s<<<dim3(4, 64, 1), 256, 0, stream>>>(
      ehi, elo, w1thi, w1tlo, b1, nullptr, z1hi, z1lo,
      8192, 512, 768, MLP_SLOPE, 1);
  // 10. z2 = LR(z1 @ W2 + b2) fp32
  gemm_bf16s<<<dim3(2, 64, 1), 256, 0, stream>>>(
      z1hi, z1lo, w2thi, w2tlo, b2, z2, nullptr, nullptr,
      8192, 256, 512, MLP_SLOPE, 1);
  // 11. edge dots
  pred_kernel<<<(E * 64 + 255) / 256, 256, 0, stream>>>(z2, ts, out, E);
}